// Round 2
// baseline (440.993 us; speedup 1.0000x reference)
//
#include <hip/hip_runtime.h>

// LengthRegulator: B=32, T=1024, D=384, MAX_LEN=8192
// out0: (B, MAX_LEN, D) f32 gather of x rows per searchsorted(cumsum(duration), frame, 'right')
// out1: (B,) mel_len = cumsum(duration)[:, -1], float-coded in d_out tail (harness-verified).
//
// R1 evidence: extra 12288-block launch is free; NT vs plain on pure-write tail is a wash.
// R2 change: single fused output pass, plain dwordx4 stores everywhere (the store path
// rocclr's fill demonstrably runs at 6.36 TB/s on this chip). NT removed entirely.

#define LR_B 32
#define LR_T 1024
#define LR_D 384
#define LR_MAXLEN 8192
#define LR_D4 (LR_D / 4)                    // 96 float4 per row
#define LR_BATCH_F4 (LR_MAXLEN * LR_D4)     // 786432 float4 per batch image
#define LR_UNROLL 8
#define LR_BLK 256
#define LR_BLK_F4 (LR_BLK * LR_UNROLL)      // 2048 float4 per block
#define LR_NBLK (LR_BATCH_F4 / LR_BLK_F4)   // 384 blocks per batch, exact

typedef float fx4 __attribute__((ext_vector_type(4)));

// Kernel A: per-batch inclusive scan of durations via wave shuffles.
// Emits mel_len (float-coded for out1, int for device use) and the
// frame -> source-offset table for the VALID prefix only:
//   src_ws[b*MAX_LEN + f] = (b*T + token)*D4   for f < mel_len[b]
// (frames >= mel_len are never read by the consumer below.)
__global__ __launch_bounds__(LR_T) void lr_scan_scatter(
    const int* __restrict__ dur,     // (B, T)
    int* __restrict__ src_ws,        // (B, MAX_LEN)
    int* __restrict__ mel_i,         // (B,) int copy for device consumers
    float* __restrict__ mel_out)     // (B,) float-coded int for out1
{
    const int b = blockIdx.x;
    const int t = threadIdx.x;
    const int lane = t & 63;
    const int wave = t >> 6;         // 16 waves

    const int d = dur[b * LR_T + t];

    // Inclusive scan within the wave (6 shuffle steps, no barriers)
    int v = d;
    #pragma unroll
    for (int off = 1; off < 64; off <<= 1) {
        int n = __shfl_up(v, off, 64);
        if (lane >= off) v += n;
    }

    __shared__ int wsum[16];
    __shared__ int woff[16];
    if (lane == 63) wsum[wave] = v;
    __syncthreads();

    // Scan the 16 wave sums inside wave 0
    if (wave == 0 && lane < 16) {
        int s = wsum[lane];
        #pragma unroll
        for (int off = 1; off < 16; off <<= 1) {
            int n = __shfl_up(s, off, 64);
            if (lane >= off) s += n;
        }
        woff[lane] = s;              // inclusive scan of wave sums
    }
    __syncthreads();

    const int base  = (wave == 0) ? 0 : woff[wave - 1];
    const int end   = base + v;      // inclusive csum at token t
    const int start = end - d;
    const int total = woff[15];      // mel_len, <= 7*1024 < MAX_LEN

    if (t == 0) { mel_out[b] = (float)total; mel_i[b] = total; }

    int* row = src_ws + b * LR_MAXLEN;
    const int src_off = (b * LR_T + t) * LR_D4;   // float4 offset of token row
    for (int f = start; f < end; ++f) row[f] = src_off;   // <= 7 iterations
}

// Kernel B: single pass over the output. Three-way block classification:
// fully-valid (gather), fully-invalid (zero stream), boundary (~1/batch, predicated).
// Plain stores everywhere. Grid: (LR_NBLK, LR_B).
__global__ __launch_bounds__(LR_BLK) void lr_write(
    const fx4* __restrict__ x,       // (B, T, D4)
    const int* __restrict__ src_ws,  // (B, MAX_LEN)
    const int* __restrict__ mel_i,   // (B,)
    fx4* __restrict__ out)           // (B, MAX_LEN, D4)
{
    const int b = blockIdx.y;
    const int mel = mel_i[b];
    const unsigned fb0 = blockIdx.x * (unsigned)LR_BLK_F4;      // f4 offset in batch
    const unsigned f_first = fb0 / LR_D4;
    const unsigned f_last  = (fb0 + LR_BLK_F4 - 1) / LR_D4;

    fx4* __restrict__ outb = out + (size_t)b * LR_BATCH_F4;
    const unsigned base = fb0 + threadIdx.x;

    if ((int)f_last < mel) {
        // Fully valid block: unpredicated gather + plain store.
        const int* __restrict__ row = src_ws + b * LR_MAXLEN;
        #pragma unroll
        for (int u = 0; u < LR_UNROLL; ++u) {
            const unsigned g = base + u * LR_BLK;
            const unsigned frame = g / LR_D4;                   // magic-mul div by 96
            const unsigned e = g - frame * LR_D4;
            outb[g] = x[(unsigned)row[frame] + e];
        }
    } else if ((int)f_first >= mel) {
        // Fully invalid block: pure zero write stream (the 6.3 TB/s fill pattern).
        const fx4 z = (fx4)(0.f, 0.f, 0.f, 0.f);
        #pragma unroll
        for (int u = 0; u < LR_UNROLL; ++u) {
            outb[base + u * LR_BLK] = z;
        }
    } else {
        // Boundary block: predicate BOTH the table load and the x load
        // (src_ws is uninitialized past mel).
        const int* __restrict__ row = src_ws + b * LR_MAXLEN;
        #pragma unroll
        for (int u = 0; u < LR_UNROLL; ++u) {
            const unsigned g = base + u * LR_BLK;
            const unsigned frame = g / LR_D4;
            fx4 v = (fx4)(0.f, 0.f, 0.f, 0.f);
            if ((int)frame < mel) {
                const unsigned e = g - frame * LR_D4;
                v = x[(unsigned)row[frame] + e];
            }
            outb[g] = v;
        }
    }
}

extern "C" void kernel_launch(void* const* d_in, const int* in_sizes, int n_in,
                              void* d_out, int out_size, void* d_ws, size_t ws_size,
                              hipStream_t stream) {
    const float* x   = (const float*)d_in[0];
    const int*   dur = (const int*)d_in[1];
    // d_in[2] = max_len (scalar on device) -- constant 8192 for this problem.

    float* out0 = (float*)d_out;                          // (B, MAX_LEN, D)
    float* mel  = out0 + (size_t)LR_B * LR_MAXLEN * LR_D; // (B,) tail
    int*   src_ws = (int*)d_ws;                           // B*MAX_LEN ints = 1 MB
    int*   mel_i  = src_ws + LR_B * LR_MAXLEN;            // (B,) ints after table

    lr_scan_scatter<<<LR_B, LR_T, 0, stream>>>(dur, src_ws, mel_i, mel);

    const dim3 grid(LR_NBLK, LR_B);
    lr_write<<<grid, LR_BLK, 0, stream>>>(
        (const fx4*)x, src_ws, mel_i, (fx4*)out0);
}

// Round 4
// 439.488 us; speedup vs baseline: 1.0034x; 1.0034x over previous
//
#include <hip/hip_runtime.h>

// LengthRegulator: B=32, T=1024, D=384, MAX_LEN=8192
// out0: (B, MAX_LEN, D) f32 gather of x rows per searchsorted(cumsum(duration), frame, 'right')
// out1: (B,) mel_len = cumsum(duration)[:, -1], float-coded in d_out tail (harness-verified).
//
// Ledger: R0->R1 NT-vs-plain tail + extra launch = neutral; R1->R2 NT-vs-plain gather
// + fused single pass = neutral. Store path exonerated (matches 6.35 TB/s fill pattern).
// R3: attack the READ side -- XCD-aware block swizzle (x-row reuse -> same-XCD L2) +
// per-block frame table staged once in LDS (kills the 2-level global dependent chain).
// R4: identical resubmit of R3 -- the R3 bench died to a container-acquisition
// failure before running; re-run the same experiment before changing variables.

#define LR_B 32
#define LR_T 1024
#define LR_D 384
#define LR_MAXLEN 8192
#define LR_D4 (LR_D / 4)                    // 96 float4 per row
#define LR_BATCH_F4 (LR_MAXLEN * LR_D4)     // 786432 float4 per batch image
#define LR_UNROLL 8
#define LR_BLK 256
#define LR_BLK_F4 (LR_BLK * LR_UNROLL)      // 2048 float4 per block
#define LR_NBLK (LR_BATCH_F4 / LR_BLK_F4)   // 384 blocks per batch, exact
#define LR_NXCD 8
#define LR_CHUNK (LR_NBLK / LR_NXCD)        // 48 blocks per XCD per batch, exact
#define LR_NF_MAX 24                        // frames touched per block: <= 22

typedef float fx4 __attribute__((ext_vector_type(4)));

// Kernel A: per-batch inclusive scan of durations via wave shuffles.
// Emits mel_len and the frame -> source-offset table for the VALID prefix only:
//   src_ws[b*MAX_LEN + f] = (b*T + token)*D4   for f < mel_len[b]
__global__ __launch_bounds__(LR_T) void lr_scan_scatter(
    const int* __restrict__ dur,     // (B, T)
    int* __restrict__ src_ws,        // (B, MAX_LEN)
    int* __restrict__ mel_i,         // (B,) int copy for device consumers
    float* __restrict__ mel_out)     // (B,) float-coded int for out1
{
    const int b = blockIdx.x;
    const int t = threadIdx.x;
    const int lane = t & 63;
    const int wave = t >> 6;         // 16 waves

    const int d = dur[b * LR_T + t];

    // Inclusive scan within the wave (6 shuffle steps, no barriers)
    int v = d;
    #pragma unroll
    for (int off = 1; off < 64; off <<= 1) {
        int n = __shfl_up(v, off, 64);
        if (lane >= off) v += n;
    }

    __shared__ int wsum[16];
    __shared__ int woff[16];
    if (lane == 63) wsum[wave] = v;
    __syncthreads();

    if (wave == 0 && lane < 16) {
        int s = wsum[lane];
        #pragma unroll
        for (int off = 1; off < 16; off <<= 1) {
            int n = __shfl_up(s, off, 64);
            if (lane >= off) s += n;
        }
        woff[lane] = s;              // inclusive scan of wave sums
    }
    __syncthreads();

    const int base  = (wave == 0) ? 0 : woff[wave - 1];
    const int end   = base + v;      // inclusive csum at token t
    const int start = end - d;
    const int total = woff[15];      // mel_len, <= 7*1024 < MAX_LEN

    if (t == 0) { mel_out[b] = (float)total; mel_i[b] = total; }

    int* row = src_ws + b * LR_MAXLEN;
    const int src_off = (b * LR_T + t) * LR_D4;   // float4 offset of token row
    for (int f = start; f < end; ++f) row[f] = src_off;   // <= 7 iterations
}

// Kernel B: single pass over the output, grid (LR_NBLK, LR_B).
// XCD swizzle: linear dispatch index (bx + by*384, 384%8==0) round-robins XCDs
// as bx%8 -> remap so each XCD owns a CONTIGUOUS 48-block frame chunk per batch;
// x-row reuse (~3.5 consecutive frames) then hits the same XCD's L2.
// The <=22 table entries per block are staged once in LDS (coalesced), so the
// per-element path is LDS-lookup -> x-load -> store.
__global__ __launch_bounds__(LR_BLK) void lr_write(
    const fx4* __restrict__ x,       // (B, T, D4)
    const int* __restrict__ src_ws,  // (B, MAX_LEN)
    const int* __restrict__ mel_i,   // (B,)
    fx4* __restrict__ out)           // (B, MAX_LEN, D4)
{
    const int b = blockIdx.y;
    const unsigned bx = blockIdx.x;
    const unsigned wbx = (bx & 7u) * LR_CHUNK + (bx >> 3);  // bijective, 384=8*48

    const int mel = mel_i[b];
    const unsigned fb0 = wbx * (unsigned)LR_BLK_F4;         // f4 offset in batch
    const unsigned f_first = fb0 / LR_D4;
    const unsigned f_last  = (fb0 + LR_BLK_F4 - 1) / LR_D4;
    const int nf = (int)(f_last - f_first) + 1;             // <= 22

    fx4* __restrict__ outb = out + (size_t)b * LR_BATCH_F4;
    const unsigned base = fb0 + threadIdx.x;

    if ((int)f_first >= mel) {
        // Fully invalid block: pure zero write stream (the 6.35 TB/s fill pattern).
        const fx4 z = (fx4)(0.f, 0.f, 0.f, 0.f);
        #pragma unroll
        for (int u = 0; u < LR_UNROLL; ++u) {
            outb[base + u * LR_BLK] = z;
        }
        return;
    }

    // Stage this block's frame table slice in LDS.
    __shared__ int sfr[LR_NF_MAX];
    const int tid = (int)threadIdx.x;
    if (tid < nf) {
        const int f = (int)f_first + tid;
        sfr[tid] = (f < mel) ? src_ws[b * LR_MAXLEN + f] : -1;
    }
    __syncthreads();

    if ((int)f_last < mel) {
        // Fully valid block: unpredicated gather.
        #pragma unroll
        for (int u = 0; u < LR_UNROLL; ++u) {
            const unsigned g = base + u * LR_BLK;
            const unsigned frame = g / LR_D4;               // magic-mul div by 96
            const unsigned e = g - frame * LR_D4;
            const int s = sfr[frame - f_first];
            outb[g] = x[(unsigned)s + e];
        }
    } else {
        // Boundary block (~1 per batch): predicated on the LDS-resident table.
        #pragma unroll
        for (int u = 0; u < LR_UNROLL; ++u) {
            const unsigned g = base + u * LR_BLK;
            const unsigned frame = g / LR_D4;
            const unsigned e = g - frame * LR_D4;
            const int s = sfr[frame - f_first];
            fx4 v = (fx4)(0.f, 0.f, 0.f, 0.f);
            if (s >= 0) v = x[(unsigned)s + e];
            outb[g] = v;
        }
    }
}

extern "C" void kernel_launch(void* const* d_in, const int* in_sizes, int n_in,
                              void* d_out, int out_size, void* d_ws, size_t ws_size,
                              hipStream_t stream) {
    const float* x   = (const float*)d_in[0];
    const int*   dur = (const int*)d_in[1];
    // d_in[2] = max_len (scalar on device) -- constant 8192 for this problem.

    float* out0 = (float*)d_out;                          // (B, MAX_LEN, D)
    float* mel  = out0 + (size_t)LR_B * LR_MAXLEN * LR_D; // (B,) tail
    int*   src_ws = (int*)d_ws;                           // B*MAX_LEN ints = 1 MB
    int*   mel_i  = src_ws + LR_B * LR_MAXLEN;            // (B,) ints after table

    lr_scan_scatter<<<LR_B, LR_T, 0, stream>>>(dur, src_ws, mel_i, mel);

    const dim3 grid(LR_NBLK, LR_B);
    lr_write<<<grid, LR_BLK, 0, stream>>>(
        (const fx4*)x, src_ws, mel_i, (fx4*)out0);
}